// Round 7
// baseline (476.809 us; speedup 1.0000x reference)
//
#include <hip/hip_runtime.h>
#include <hip/hip_fp16.h>
#include <math.h>

#define N_NODES 50000
#define N_EDGES 1600000
#define NB_BUCKETS 391      // ceil(50000/128), bucket = dst>>7
#define PART_CHUNK 8192
#define NCHUNK 196          // ceil(N_EDGES / PART_CHUNK)
#define CAP 6144            // per-bucket slot stride; mean 4096, sigma 64 -> 32 sigma margin
#define ZSTRIDE 32          // z row = 32 halves = 64B, one cache line
#define ASTRIDE 29          // LDS acc row stride (coprime with 32 banks)

// ---------- DPP helpers (VALU-pipe cross-lane, no LDS) ----------
template<int CTRL>
__device__ inline float dpp_mov(float x){
    return __int_as_float(__builtin_amdgcn_update_dpp(0, __float_as_int(x), CTRL, 0xf, 0xf, false));
}
__device__ inline float wave_sum_dpp(float x){
    x += dpp_mov<0x111>(x);   // row_shr:1
    x += dpp_mov<0x112>(x);   // row_shr:2
    x += dpp_mov<0x114>(x);   // row_shr:4
    x += dpp_mov<0x118>(x);   // row_shr:8
    x += dpp_mov<0x142>(x);   // row_bcast:15
    x += dpp_mov<0x143>(x);   // row_bcast:31
    return x;
}
__device__ inline float lane63(float x){
    return __int_as_float(__builtin_amdgcn_readlane(__float_as_int(x), 63));
}
#define DPP_XOR1 0xB1   // quad_perm [1,0,3,2]
#define DPP_XOR2 0x4E   // quad_perm [2,3,0,1]

// ---------- complex 2x2 helpers ----------
struct C2 { float x, y; };
__device__ inline C2 mkc(float x, float y){ C2 r; r.x=x; r.y=y; return r; }
__device__ inline C2 cmul(C2 a, C2 b){ return mkc(a.x*b.x - a.y*b.y, a.x*b.y + a.y*b.x); }
__device__ inline C2 cadd(C2 a, C2 b){ return mkc(a.x+b.x, a.y+b.y); }

// ---------- K0: probe dtype + pair coefficients + zero bucketFill/G ----------
__global__ __launch_bounds__(256) void k_init(const float* __restrict__ qw,
        const void* __restrict__ ei, float4* __restrict__ cmat,
        int* __restrict__ flag, int* __restrict__ bucketFill, float* __restrict__ G){
    int t = threadIdx.x;
    for (int i = t; i < NB_BUCKETS; i += 256) bucketFill[i] = 0;
    for (int i = t; i < 784; i += 256) G[i] = 0.f;
    if (t == 255){
        const long long* e64 = (const long long*)ei;
        int ok = 1;
        for (int i = 0; i < 64; i++){
            long long v = e64[i];
            if (v < 0 || v >= N_NODES) ok = 0;
        }
        flag[0] = ok;
    }
    if (t < 28){
        int p = t;
        int a = 0; { int rem = p, q = 0; while (rem >= 7 - q){ rem -= 7 - q; q++; } a = q; }
        C2 M00 = mkc(1,0), M01 = mkc(0,0), M10 = mkc(0,0), M11 = mkc(1,0);
        for (int k = 0; k < 6; k++){
            float th = 0.5f * qw[p*6 + k];
            float s, c; sincosf(th, &s, &c);
            C2 R00, R01, R10, R11;
            int type = k % 3;
            if (type == 0){      // Rx
                R00 = mkc(c,0); R01 = mkc(0,-s); R10 = mkc(0,-s); R11 = mkc(c,0);
            } else if (type == 1){ // Ry
                R00 = mkc(c,0); R01 = mkc(-s,0); R10 = mkc(s,0); R11 = mkc(c,0);
            } else {             // Rz
                R00 = mkc(c,-s); R01 = mkc(0,0); R10 = mkc(0,0); R11 = mkc(c,s);
            }
            C2 N00 = cadd(cmul(R00,M00), cmul(R01,M10));
            C2 N01 = cadd(cmul(R00,M01), cmul(R01,M11));
            C2 N10 = cadd(cmul(R10,M00), cmul(R11,M10));
            C2 N11 = cadd(cmul(R10,M01), cmul(R11,M11));
            M00=N00; M01=N01; M10=N10; M11=N11;
        }
        float B00  = (M00.x*M00.x + M00.y*M00.y) - (M10.x*M10.x + M10.y*M10.y);
        float B11  = (M01.x*M01.x + M01.y*M01.y) - (M11.x*M11.x + M11.y*M11.y);
        float B01r = (M00.x*M01.x + M00.y*M01.y) - (M10.x*M11.x + M10.y*M11.y);
        cmat[p] = make_float4(0.5f + 0.5f*B11, 0.5f*(B00 - B11), B01r, (float)a);
    }
}

__device__ inline int get_edge(const void* ei, int is64, long long idx){
    if (is64) return (int)((const long long*)ei)[idx];
    return ((const int*)ei)[idx];
}

// ---------- one-pass partition: chunk -> LDS bucket sort -> atomic reserve -> dense copy ----------
// pairs laid out bucket-major with fixed stride CAP; entry = (dst<<16)|src
__global__ __launch_bounds__(256) void k_part(const void* __restrict__ ei,
        const int* __restrict__ flag, int* __restrict__ bucketFill,
        unsigned* __restrict__ pairs){
    __shared__ int hist[NB_BUCKETS];
    __shared__ int cntb[NB_BUCKETS];
    __shared__ int cursor[NB_BUCKETS];
    __shared__ int copyBase[NB_BUCKETS];
    __shared__ unsigned sorted[PART_CHUNK];
    int tid = threadIdx.x, c = blockIdx.x;
    long long base = (long long)c * PART_CHUNK;
    int cnt = (int)((N_EDGES - base < PART_CHUNK) ? (N_EDGES - base) : PART_CHUNK);
    for (int i = tid; i < NB_BUCKETS; i += 256) hist[i] = 0;
    __syncthreads();
    int is64 = flag[0];
    for (int i = tid; i < cnt; i += 256){
        int dst = get_edge(ei, is64, (long long)N_EDGES + base + i);
        atomicAdd(&hist[dst >> 7], 1);
    }
    __syncthreads();
    for (int i = tid; i < NB_BUCKETS; i += 256) cntb[i] = hist[i];
    __syncthreads();
    for (int ofs = 1; ofs < NB_BUCKETS; ofs <<= 1){   // inclusive Hillis-Steele scan
        int i0 = tid, i1 = tid + 256;
        bool a0 = i0 < NB_BUCKETS, a1 = i1 < NB_BUCKETS;
        int v0 = 0, v1 = 0;
        if (a0) v0 = hist[i0] + (i0 >= ofs ? hist[i0 - ofs] : 0);
        if (a1) v1 = hist[i1] + (i1 >= ofs ? hist[i1 - ofs] : 0);
        __syncthreads();
        if (a0) hist[i0] = v0;
        if (a1) hist[i1] = v1;
        __syncthreads();
    }
    for (int i = tid; i < NB_BUCKETS; i += 256){
        int ls = hist[i] - cntb[i];                    // local exclusive start
        int gbase = i*CAP + atomicAdd(&bucketFill[i], cntb[i]);
        copyBase[i] = gbase - ls;
        cursor[i] = ls;
    }
    __syncthreads();
    for (int i = tid; i < cnt; i += 256){
        int src = get_edge(ei, is64, base + i);
        int dst = get_edge(ei, is64, (long long)N_EDGES + base + i);
        int pos = atomicAdd(&cursor[dst >> 7], 1);
        sorted[pos] = ((unsigned)dst << 16) | (unsigned)src;
    }
    __syncthreads();
    for (int i = tid; i < cnt; i += 256){
        unsigned v = sorted[i];
        int b = (int)(v >> 23);                        // dst>>7
        pairs[copyBase[b] + i] = v;
    }
}

// ---------- per-bucket degree -> dinv ----------
__global__ __launch_bounds__(256) void k_deg(const unsigned* __restrict__ pairs,
        const int* __restrict__ bucketFill, float* __restrict__ dinv){
    __shared__ int hist[128];
    int b = blockIdx.x, t = threadIdx.x;
    int cnt = bucketFill[b];
    const unsigned* P = pairs + (size_t)b*CAP;
    if (t < 128) hist[t] = 0;
    __syncthreads();
    for (int i = t; i < cnt; i += 256)
        atomicAdd(&hist[(P[i] >> 16) & 127], 1);
    __syncthreads();
    if (t < 128){
        int n = b*128 + t;
        if (n < N_NODES) dinv[n] = rsqrtf((float)(hist[t] + 1));
    }
}

// ---------- quantum features: one wave per node, DPP reductions, fp16 z ----------
__global__ __launch_bounds__(256) void k_feat(const float* __restrict__ x,
        const float* __restrict__ dinv, const float4* __restrict__ cmat,
        __half* __restrict__ z){
    int wave = threadIdx.x >> 6;
    int lane = threadIdx.x & 63;
    int n = blockIdx.x*4 + wave;
    const float4 v = ((const float4*)(x + (size_t)n*256))[lane];
    float persq = v.x*v.x + v.y*v.y + v.z*v.z + v.w*v.w;

    float red[15];
    red[0] = persq;
    red[1] = v.x*v.x + v.y*v.y;        // S0 qubit6
    red[2] = v.x*v.z + v.y*v.w;        // X qubit6
    {   // j=0: xor mask 1 via DPP quad_perm
        float px = dpp_mov<DPP_XOR1>(v.x), py = dpp_mov<DPP_XOR1>(v.y);
        float pz = dpp_mov<DPP_XOR1>(v.z), pw = dpp_mov<DPP_XOR1>(v.w);
        red[3] = v.x*px + v.y*py + v.z*pz + v.w*pw;
        red[9] = (lane & 1) ? 0.f : persq;
    }
    {   // j=1: xor mask 2 via DPP quad_perm
        float px = dpp_mov<DPP_XOR2>(v.x), py = dpp_mov<DPP_XOR2>(v.y);
        float pz = dpp_mov<DPP_XOR2>(v.z), pw = dpp_mov<DPP_XOR2>(v.w);
        red[4] = v.x*px + v.y*py + v.z*pz + v.w*pw;
        red[10] = (lane & 2) ? 0.f : persq;
    }
    #pragma unroll
    for (int j = 2; j < 6; j++){
        float px = __shfl_xor(v.x, 1 << j), py = __shfl_xor(v.y, 1 << j);
        float pz = __shfl_xor(v.z, 1 << j), pw = __shfl_xor(v.w, 1 << j);
        red[3 + j] = v.x*px + v.y*py + v.z*pz + v.w*pw;
        red[9 + j] = ((lane >> j) & 1) ? 0.0f : persq;
    }
    float S[15];
    #pragma unroll
    for (int k = 0; k < 15; k++) S[k] = lane63(wave_sum_dpp(red[k]));

    if (lane < 28){
        float4 cm = cmat[lane];
        int ap = (int)cm.w;
        float S0a = (ap==6) ? S[1] :
                    (ap==0 ? S[14] : ap==1 ? S[13] : ap==2 ? S[12] :
                     ap==3 ? S[11] : ap==4 ? S[10] : S[9]);
        float Xa  = (ap==6) ? S[2] :
                    0.5f*(ap==0 ? S[8] : ap==1 ? S[7] : ap==2 ? S[6] :
                          ap==3 ? S[5] : ap==4 ? S[4] : S[3]);
        float feat = cm.x + (cm.y*S0a + cm.z*Xa) / S[0];
        z[(size_t)n*ZSTRIDE + lane] = __float2half(dinv[n] * feat);
    } else if (lane < 32){
        z[(size_t)n*ZSTRIDE + lane] = __float2half(0.f);   // zero pad
    }
}

// ---------- fused aggregate + relu + Gram partial (block per bucket) ----------
__device__ inline void unpack2(unsigned u, float& a, float& b){
    float2 f = __half22float2(__builtin_bit_cast(__half2, u));
    a = f.x; b = f.y;
}

__global__ __launch_bounds__(256) void k_agg(const unsigned* __restrict__ pairs,
        const int* __restrict__ bucketFill, const __half* __restrict__ z,
        const float* __restrict__ dinv, float* __restrict__ G){
    __shared__ float acc[128*ASTRIDE];
    int b = blockIdx.x, t = threadIdx.x;
    for (int i = t; i < 128*ASTRIDE; i += 256) acc[i] = 0.f;
    __syncthreads();
    int cnt = bucketFill[b];
    const unsigned* P = pairs + (size_t)b*CAP;
    for (int i = t; i < cnt; i += 256){
        unsigned v = P[i];
        int d = (v >> 16) & 127;
        int src = v & 0xffffu;
        const uint4* rp = (const uint4*)(z + (size_t)src*ZSTRIDE);
        uint4 w0 = rp[0], w1 = rp[1], w2 = rp[2];
        uint2 w3 = ((const uint2*)rp)[6];
        float f[28];
        unpack2(w0.x, f[0],  f[1]);  unpack2(w0.y, f[2],  f[3]);
        unpack2(w0.z, f[4],  f[5]);  unpack2(w0.w, f[6],  f[7]);
        unpack2(w1.x, f[8],  f[9]);  unpack2(w1.y, f[10], f[11]);
        unpack2(w1.z, f[12], f[13]); unpack2(w1.w, f[14], f[15]);
        unpack2(w2.x, f[16], f[17]); unpack2(w2.y, f[18], f[19]);
        unpack2(w2.z, f[20], f[21]); unpack2(w2.w, f[22], f[23]);
        unpack2(w3.x, f[24], f[25]); unpack2(w3.y, f[26], f[27]);
        float* arow = acc + d*ASTRIDE;
        #pragma unroll
        for (int k = 0; k < 28; k++) atomicAdd(&arow[k], f[k]);
    }
    __syncthreads();
    // self + relu in place (invalid nodes -> 0 so Gram partial is unaffected)
    for (int e = t; e < 128*28; e += 256){
        int d = e / 28, k = e - 28*d;
        int n = b*128 + d;
        float val = 0.f;
        if (n < N_NODES){
            float self = __half2float(z[(size_t)n*ZSTRIDE + k]);
            val = fmaxf((acc[d*ASTRIDE + k] + self) * dinv[n], 0.f);
        }
        acc[d*ASTRIDE + k] = val;
    }
    __syncthreads();
    // Gram partial over this bucket's 128 rows: 2x2 tile per thread (196 active)
    if (t < 196){
        int ti = t / 14, tj = t % 14;
        int i0 = 2*ti, j0 = 2*tj;
        float c00 = 0.f, c01 = 0.f, c10 = 0.f, c11 = 0.f;
        for (int nn = 0; nn < 128; nn++){
            const float* r = acc + nn*ASTRIDE;
            float a0 = r[i0], a1 = r[i0+1], b0 = r[j0], b1 = r[j0+1];
            c00 += a0*b0; c01 += a0*b1; c10 += a1*b0; c11 += a1*b1;
        }
        atomicAdd(&G[(i0  )*28 + j0  ], c00);
        atomicAdd(&G[(i0  )*28 + j0+1], c01);
        atomicAdd(&G[(i0+1)*28 + j0  ], c10);
        atomicAdd(&G[(i0+1)*28 + j0+1], c11);
    }
}

// ---------- fused MLP: h = relu(G@W1^T + b1); out = sigmoid(h@W2^T + b2) ----------
__global__ __launch_bounds__(256) void k_mlp(const float* __restrict__ G,
        const float* __restrict__ W1, const float* __restrict__ b1,
        const float* __restrict__ W2, const float* __restrict__ b2,
        float* __restrict__ outp){
    __shared__ float part[256];
    __shared__ float h[128];
    int t = threadIdx.x;
    int j = t & 127, halfsel = t >> 7;
    const float* w = W1 + (size_t)j*784 + halfsel*392;
    const float* g = G + halfsel*392;
    float s = 0.f;
    for (int i = 0; i < 392; i++) s += g[i] * w[i];
    part[t] = s;
    __syncthreads();
    if (t < 128) h[t] = fmaxf(part[t] + part[t+128] + b1[t], 0.f) * W2[t];
    __syncthreads();
    for (int ofs = 64; ofs > 0; ofs >>= 1){
        if (t < ofs) h[t] += h[t + ofs];
        __syncthreads();
    }
    if (t == 0) outp[0] = 1.f / (1.f + expf(-(h[0] + b2[0])));
}

extern "C" void kernel_launch(void* const* d_in, const int* in_sizes, int n_in,
                              void* d_out, int out_size, void* d_ws, size_t ws_size,
                              hipStream_t stream){
    const float* x  = (const float*)d_in[0];
    const void*  ei = d_in[1];
    const float* qw = (const float*)d_in[2];
    const float* W1 = (const float*)d_in[3];
    const float* b1 = (const float*)d_in[4];
    const float* W2 = (const float*)d_in[5];
    const float* b2 = (const float*)d_in[6];
    float* outp = (float*)d_out;

    char* base = (char*)d_ws;
    __half*   z     = (__half*)base;   base += (size_t)N_NODES*ZSTRIDE*2;   // 3.2 MB
    unsigned* pairs = (unsigned*)base; base += (size_t)NB_BUCKETS*CAP*4;    // 9.6 MB
    float*    dinv  = (float*)base;    base += (size_t)N_NODES*4;           // 0.2 MB
    float4*   cmat  = (float4*)base;   base += 448;
    float*    G     = (float*)base;    base += 4096;
    int*      bucketFill = (int*)base; base += 2048;
    int*      flag  = (int*)base;      base += 16;

    k_init<<<1, 256, 0, stream>>>(qw, ei, cmat, flag, bucketFill, G);
    k_part<<<NCHUNK, 256, 0, stream>>>(ei, flag, bucketFill, pairs);
    k_deg<<<NB_BUCKETS, 256, 0, stream>>>(pairs, bucketFill, dinv);
    k_feat<<<N_NODES/4, 256, 0, stream>>>(x, dinv, cmat, z);
    k_agg<<<NB_BUCKETS, 256, 0, stream>>>(pairs, bucketFill, z, dinv, G);
    k_mlp<<<1, 256, 0, stream>>>(G, W1, b1, W2, b2, outp);
}

// Round 8
// 226.523 us; speedup vs baseline: 2.1049x; 2.1049x over previous
//
#include <hip/hip_runtime.h>
#include <hip/hip_fp16.h>
#include <math.h>

#define N_NODES 50000
#define N_EDGES 1600000
#define NB_BUCKETS 391      // ceil(50000/128), bucket = dst>>7
#define PART_CHUNK 8192
#define NCHUNK 196          // ceil(N_EDGES / PART_CHUNK)
#define CAP 6144            // per-bucket slot stride; mean 4096, sigma ~64
#define ZSTRIDE 32          // z row = 32 halves = 64B, one cache line

// ---------- DPP helpers (VALU-pipe cross-lane, no LDS) ----------
template<int CTRL>
__device__ inline float dpp_mov(float x){
    return __int_as_float(__builtin_amdgcn_update_dpp(0, __float_as_int(x), CTRL, 0xf, 0xf, false));
}
__device__ inline float wave_sum_dpp(float x){
    x += dpp_mov<0x111>(x);   // row_shr:1
    x += dpp_mov<0x112>(x);   // row_shr:2
    x += dpp_mov<0x114>(x);   // row_shr:4
    x += dpp_mov<0x118>(x);   // row_shr:8
    x += dpp_mov<0x142>(x);   // row_bcast:15
    x += dpp_mov<0x143>(x);   // row_bcast:31
    return x;
}
__device__ inline float lane63(float x){
    return __int_as_float(__builtin_amdgcn_readlane(__float_as_int(x), 63));
}
#define DPP_XOR1 0xB1   // quad_perm [1,0,3,2]
#define DPP_XOR2 0x4E   // quad_perm [2,3,0,1]

// ---------- complex 2x2 helpers ----------
struct C2 { float x, y; };
__device__ inline C2 mkc(float x, float y){ C2 r; r.x=x; r.y=y; return r; }
__device__ inline C2 cmul(C2 a, C2 b){ return mkc(a.x*b.x - a.y*b.y, a.x*b.y + a.y*b.x); }
__device__ inline C2 cadd(C2 a, C2 b){ return mkc(a.x+b.x, a.y+b.y); }

// ---------- K0: probe dtype + pair coefficients + zero bucketFill/G ----------
__global__ __launch_bounds__(256) void k_init(const float* __restrict__ qw,
        const void* __restrict__ ei, float4* __restrict__ cmat,
        int* __restrict__ flag, int* __restrict__ bucketFill, float* __restrict__ G){
    int t = threadIdx.x;
    for (int i = t; i < NB_BUCKETS; i += 256) bucketFill[i] = 0;
    for (int i = t; i < 784; i += 256) G[i] = 0.f;
    if (t == 255){
        const long long* e64 = (const long long*)ei;
        int ok = 1;
        for (int i = 0; i < 64; i++){
            long long v = e64[i];
            if (v < 0 || v >= N_NODES) ok = 0;
        }
        flag[0] = ok;
    }
    if (t < 28){
        int p = t;
        int a = 0; { int rem = p, q = 0; while (rem >= 7 - q){ rem -= 7 - q; q++; } a = q; }
        C2 M00 = mkc(1,0), M01 = mkc(0,0), M10 = mkc(0,0), M11 = mkc(1,0);
        for (int k = 0; k < 6; k++){
            float th = 0.5f * qw[p*6 + k];
            float s, c; sincosf(th, &s, &c);
            C2 R00, R01, R10, R11;
            int type = k % 3;
            if (type == 0){      // Rx
                R00 = mkc(c,0); R01 = mkc(0,-s); R10 = mkc(0,-s); R11 = mkc(c,0);
            } else if (type == 1){ // Ry
                R00 = mkc(c,0); R01 = mkc(-s,0); R10 = mkc(s,0); R11 = mkc(c,0);
            } else {             // Rz
                R00 = mkc(c,-s); R01 = mkc(0,0); R10 = mkc(0,0); R11 = mkc(c,s);
            }
            C2 N00 = cadd(cmul(R00,M00), cmul(R01,M10));
            C2 N01 = cadd(cmul(R00,M01), cmul(R01,M11));
            C2 N10 = cadd(cmul(R10,M00), cmul(R11,M10));
            C2 N11 = cadd(cmul(R10,M01), cmul(R11,M11));
            M00=N00; M01=N01; M10=N10; M11=N11;
        }
        float B00  = (M00.x*M00.x + M00.y*M00.y) - (M10.x*M10.x + M10.y*M10.y);
        float B11  = (M01.x*M01.x + M01.y*M01.y) - (M11.x*M11.x + M11.y*M11.y);
        float B01r = (M00.x*M01.x + M00.y*M01.y) - (M10.x*M11.x + M10.y*M11.y);
        cmat[p] = make_float4(0.5f + 0.5f*B11, 0.5f*(B00 - B11), B01r, (float)a);
    }
}

__device__ inline int get_edge(const void* ei, int is64, long long idx){
    if (is64) return (int)((const long long*)ei)[idx];
    return ((const int*)ei)[idx];
}

// ---------- one-pass partition: LDS bucket sort per chunk + atomic reserve ----------
// pairs laid out bucket-major with fixed stride CAP; entry = (dst<<16)|src
__global__ __launch_bounds__(256) void k_part(const void* __restrict__ ei,
        const int* __restrict__ flag, int* __restrict__ bucketFill,
        unsigned* __restrict__ pairs){
    __shared__ int hist[NB_BUCKETS];
    __shared__ int cntb[NB_BUCKETS];
    __shared__ int cursor[NB_BUCKETS];
    __shared__ int copyBase[NB_BUCKETS];
    __shared__ unsigned sorted[PART_CHUNK];
    int tid = threadIdx.x, c = blockIdx.x;
    long long base = (long long)c * PART_CHUNK;
    int cnt = (int)((N_EDGES - base < PART_CHUNK) ? (N_EDGES - base) : PART_CHUNK);
    for (int i = tid; i < NB_BUCKETS; i += 256) hist[i] = 0;
    __syncthreads();
    int is64 = flag[0];
    for (int i = tid; i < cnt; i += 256){
        int dst = get_edge(ei, is64, (long long)N_EDGES + base + i);
        atomicAdd(&hist[dst >> 7], 1);
    }
    __syncthreads();
    for (int i = tid; i < NB_BUCKETS; i += 256) cntb[i] = hist[i];
    __syncthreads();
    for (int ofs = 1; ofs < NB_BUCKETS; ofs <<= 1){   // inclusive Hillis-Steele scan
        int i0 = tid, i1 = tid + 256;
        bool a0 = i0 < NB_BUCKETS, a1 = i1 < NB_BUCKETS;
        int v0 = 0, v1 = 0;
        if (a0) v0 = hist[i0] + (i0 >= ofs ? hist[i0 - ofs] : 0);
        if (a1) v1 = hist[i1] + (i1 >= ofs ? hist[i1 - ofs] : 0);
        __syncthreads();
        if (a0) hist[i0] = v0;
        if (a1) hist[i1] = v1;
        __syncthreads();
    }
    for (int i = tid; i < NB_BUCKETS; i += 256){
        int ls = hist[i] - cntb[i];                    // local exclusive start
        int gbase = i*CAP + atomicAdd(&bucketFill[i], cntb[i]);
        copyBase[i] = gbase - ls;
        cursor[i] = ls;
    }
    __syncthreads();
    for (int i = tid; i < cnt; i += 256){
        int src = get_edge(ei, is64, base + i);
        int dst = get_edge(ei, is64, (long long)N_EDGES + base + i);
        int pos = atomicAdd(&cursor[dst >> 7], 1);
        sorted[pos] = ((unsigned)dst << 16) | (unsigned)src;
    }
    __syncthreads();
    for (int i = tid; i < cnt; i += 256){
        unsigned v = sorted[i];
        int b = (int)(v >> 23);                        // dst>>7
        pairs[copyBase[b] + i] = v;
    }
}

// ---------- per-bucket counting sort -> ushort CSR + nodeOff + dinv ----------
__global__ __launch_bounds__(256) void k_sort(const unsigned* __restrict__ pairs,
        const int* __restrict__ bucketFill, unsigned short* __restrict__ csr,
        int* __restrict__ nodeOff, float* __restrict__ dinv){
    __shared__ unsigned short sorted[CAP];
    __shared__ int hist[128];
    __shared__ int cursor[128];
    int b = blockIdx.x, t = threadIdx.x;
    int s0 = b*CAP;
    int cnt = bucketFill[b];
    if (cnt > CAP) cnt = CAP;
    if (t < 128) hist[t] = 0;
    __syncthreads();
    for (int i = t; i < cnt; i += 256){
        unsigned v = pairs[s0 + i];
        atomicAdd(&hist[(v >> 16) & 127], 1);
    }
    __syncthreads();
    int mycnt = (t < 128) ? hist[t] : 0;
    for (int ofs = 1; ofs < 128; ofs <<= 1){
        int nv = 0;
        if (t < 128) nv = hist[t] + (t >= ofs ? hist[t - ofs] : 0);
        __syncthreads();
        if (t < 128) hist[t] = nv;
        __syncthreads();
    }
    if (t < 128){
        cursor[t] = hist[t] - mycnt;               // exclusive start
        int n = b*128 + t;
        if (n < N_NODES){
            nodeOff[n] = s0 + hist[t] - mycnt;     // index into csr (bucket-major)
            dinv[n] = rsqrtf((float)(mycnt + 1));
        }
    }
    __syncthreads();
    for (int i = t; i < cnt; i += 256){
        unsigned v = pairs[s0 + i];
        int d = (v >> 16) & 127;
        int pos = atomicAdd(&cursor[d], 1);
        sorted[pos] = (unsigned short)(v & 0xffffu);
    }
    __syncthreads();
    for (int i = t; i < cnt; i += 256) csr[s0 + i] = sorted[i];
}

// ---------- quantum features: one wave per node, DPP reductions, fp16 z ----------
__global__ __launch_bounds__(256) void k_feat(const float* __restrict__ x,
        const float* __restrict__ dinv, const float4* __restrict__ cmat,
        __half* __restrict__ z){
    int wave = threadIdx.x >> 6;
    int lane = threadIdx.x & 63;
    int n = blockIdx.x*4 + wave;
    const float4 v = ((const float4*)(x + (size_t)n*256))[lane];
    float persq = v.x*v.x + v.y*v.y + v.z*v.z + v.w*v.w;

    float red[15];
    red[0] = persq;
    red[1] = v.x*v.x + v.y*v.y;        // S0 qubit6
    red[2] = v.x*v.z + v.y*v.w;        // X qubit6
    {   // j=0: xor mask 1 via DPP quad_perm
        float px = dpp_mov<DPP_XOR1>(v.x), py = dpp_mov<DPP_XOR1>(v.y);
        float pz = dpp_mov<DPP_XOR1>(v.z), pw = dpp_mov<DPP_XOR1>(v.w);
        red[3] = v.x*px + v.y*py + v.z*pz + v.w*pw;
        red[9] = (lane & 1) ? 0.f : persq;
    }
    {   // j=1: xor mask 2 via DPP quad_perm
        float px = dpp_mov<DPP_XOR2>(v.x), py = dpp_mov<DPP_XOR2>(v.y);
        float pz = dpp_mov<DPP_XOR2>(v.z), pw = dpp_mov<DPP_XOR2>(v.w);
        red[4] = v.x*px + v.y*py + v.z*pz + v.w*pw;
        red[10] = (lane & 2) ? 0.f : persq;
    }
    #pragma unroll
    for (int j = 2; j < 6; j++){
        float px = __shfl_xor(v.x, 1 << j), py = __shfl_xor(v.y, 1 << j);
        float pz = __shfl_xor(v.z, 1 << j), pw = __shfl_xor(v.w, 1 << j);
        red[3 + j] = v.x*px + v.y*py + v.z*pz + v.w*pw;
        red[9 + j] = ((lane >> j) & 1) ? 0.0f : persq;
    }
    float S[15];
    #pragma unroll
    for (int k = 0; k < 15; k++) S[k] = lane63(wave_sum_dpp(red[k]));

    if (lane < 28){
        float4 cm = cmat[lane];
        int ap = (int)cm.w;
        float S0a = (ap==6) ? S[1] :
                    (ap==0 ? S[14] : ap==1 ? S[13] : ap==2 ? S[12] :
                     ap==3 ? S[11] : ap==4 ? S[10] : S[9]);
        float Xa  = (ap==6) ? S[2] :
                    0.5f*(ap==0 ? S[8] : ap==1 ? S[7] : ap==2 ? S[6] :
                          ap==3 ? S[5] : ap==4 ? S[4] : S[3]);
        float feat = cm.x + (cm.y*S0a + cm.z*Xa) / S[0];
        z[(size_t)n*ZSTRIDE + lane] = __float2half(dinv[n] * feat);
    } else if (lane < 32){
        z[(size_t)n*ZSTRIDE + lane] = __float2half(0.f);   // zero pad
    }
}

// ---------- GCN aggregate + relu: 4 threads/node, fp16 rows, DPP combine ----------
__device__ inline void acc_pack(unsigned u, float& a, float& b){
    float2 f = __half22float2(__builtin_bit_cast(__half2, u));
    a += f.x; b += f.y;
}
__device__ inline void acc_row(const uint4* rp, float* acc /*32*/){
    uint4 w0 = rp[0], w1 = rp[1], w2 = rp[2], w3 = rp[3];
    acc_pack(w0.x, acc[0],  acc[1]);  acc_pack(w0.y, acc[2],  acc[3]);
    acc_pack(w0.z, acc[4],  acc[5]);  acc_pack(w0.w, acc[6],  acc[7]);
    acc_pack(w1.x, acc[8],  acc[9]);  acc_pack(w1.y, acc[10], acc[11]);
    acc_pack(w1.z, acc[12], acc[13]); acc_pack(w1.w, acc[14], acc[15]);
    acc_pack(w2.x, acc[16], acc[17]); acc_pack(w2.y, acc[18], acc[19]);
    acc_pack(w2.z, acc[20], acc[21]); acc_pack(w2.w, acc[22], acc[23]);
    acc_pack(w3.x, acc[24], acc[25]); acc_pack(w3.y, acc[26], acc[27]);
    acc_pack(w3.z, acc[28], acc[29]); acc_pack(w3.w, acc[30], acc[31]);
}

__global__ __launch_bounds__(256) void k_gather(const unsigned short* __restrict__ csr,
        const int* __restrict__ nodeOff, const int* __restrict__ bucketFill,
        const __half* __restrict__ z, const float* __restrict__ dinv,
        float* __restrict__ out){
    int g = blockIdx.x*256 + threadIdx.x;
    int n = g >> 2, sub = g & 3;
    if (n >= N_NODES) return;
    int b = n >> 7, d = n & 127;
    int beg = nodeOff[n];
    int end = (d == 127 || n == N_NODES - 1) ? b*CAP + min(bucketFill[b], CAP)
                                             : nodeOff[n + 1];
    float acc[32];
    #pragma unroll
    for (int k = 0; k < 32; k++) acc[k] = 0.f;
    for (int i = beg + sub; i < end; i += 4){
        int src = csr[i];
        acc_row((const uint4*)(z + (size_t)src*ZSTRIDE), acc);
    }
    if (sub == 3) acc_row((const uint4*)(z + (size_t)n*ZSTRIDE), acc);  // self loop
    #pragma unroll
    for (int k = 0; k < 32; k++){
        acc[k] += dpp_mov<DPP_XOR1>(acc[k]);
        acc[k] += dpp_mov<DPP_XOR2>(acc[k]);
    }
    if (sub == 0){
        float dv = dinv[n];
        float4* o = (float4*)(out + (size_t)n*28);
        #pragma unroll
        for (int q = 0; q < 7; q++)
            o[q] = make_float4(fmaxf(acc[4*q+0]*dv, 0.f), fmaxf(acc[4*q+1]*dv, 0.f),
                               fmaxf(acc[4*q+2]*dv, 0.f), fmaxf(acc[4*q+3]*dv, 0.f));
    }
}

// ---------- Gram: 2x2 register tiling ----------
__global__ __launch_bounds__(256) void k_gram(const float* __restrict__ out, float* __restrict__ G){
    __shared__ float buf[64*28];
    int tid = threadIdx.x;
    bool val = tid < 196;
    int ti = val ? tid / 14 : 0, tj = val ? tid % 14 : 0;
    int i0 = 2*ti, j0 = 2*tj;
    float c00 = 0.f, c01 = 0.f, c10 = 0.f, c11 = 0.f;
    int nchunks = (N_NODES + 63) / 64;
    for (int ch = blockIdx.x; ch < nchunks; ch += gridDim.x){
        int base = ch * 64;
        int total = (N_NODES - base < 64 ? N_NODES - base : 64) * 28;
        __syncthreads();
        for (int t = tid; t < 64*28; t += 256)
            buf[t] = (t < total) ? out[(size_t)base*28 + t] : 0.f;
        __syncthreads();
        for (int nn = 0; nn < 64; nn++){
            const float* r = buf + nn*28;
            float a0 = r[i0], a1 = r[i0+1], b0 = r[j0], b1 = r[j0+1];
            c00 += a0*b0; c01 += a0*b1; c10 += a1*b0; c11 += a1*b1;
        }
    }
    if (val){
        atomicAdd(&G[(i0  )*28 + j0  ], c00);
        atomicAdd(&G[(i0  )*28 + j0+1], c01);
        atomicAdd(&G[(i0+1)*28 + j0  ], c10);
        atomicAdd(&G[(i0+1)*28 + j0+1], c11);
    }
}

// ---------- fused MLP: h = relu(G@W1^T + b1); out = sigmoid(h@W2^T + b2) ----------
__global__ __launch_bounds__(256) void k_mlp(const float* __restrict__ G,
        const float* __restrict__ W1, const float* __restrict__ b1,
        const float* __restrict__ W2, const float* __restrict__ b2,
        float* __restrict__ outp){
    __shared__ float part[256];
    __shared__ float h[128];
    int t = threadIdx.x;
    int j = t & 127, halfsel = t >> 7;
    const float* w = W1 + (size_t)j*784 + halfsel*392;
    const float* g = G + halfsel*392;
    float s = 0.f;
    for (int i = 0; i < 392; i++) s += g[i] * w[i];
    part[t] = s;
    __syncthreads();
    if (t < 128) h[t] = fmaxf(part[t] + part[t+128] + b1[t], 0.f) * W2[t];
    __syncthreads();
    for (int ofs = 64; ofs > 0; ofs >>= 1){
        if (t < ofs) h[t] += h[t + ofs];
        __syncthreads();
    }
    if (t == 0) outp[0] = 1.f / (1.f + expf(-(h[0] + b2[0])));
}

extern "C" void kernel_launch(void* const* d_in, const int* in_sizes, int n_in,
                              void* d_out, int out_size, void* d_ws, size_t ws_size,
                              hipStream_t stream){
    const float* x  = (const float*)d_in[0];
    const void*  ei = d_in[1];
    const float* qw = (const float*)d_in[2];
    const float* W1 = (const float*)d_in[3];
    const float* b1 = (const float*)d_in[4];
    const float* W2 = (const float*)d_in[5];
    const float* b2 = (const float*)d_in[6];
    float* outp = (float*)d_out;

    char* base = (char*)d_ws;
    __half*         z     = (__half*)base;         base += (size_t)N_NODES*ZSTRIDE*2;   // 3.2 MB
    float*          ob    = (float*)base;          base += (size_t)N_NODES*28*4;        // 5.6 MB
    unsigned*       pairs = (unsigned*)base;       base += (size_t)NB_BUCKETS*CAP*4;    // 9.6 MB
    unsigned short* csr   = (unsigned short*)base; base += (size_t)NB_BUCKETS*CAP*2;    // 4.8 MB
    int*            nodeOff = (int*)base;          base += (size_t)N_NODES*4;
    float*          dinv  = (float*)base;          base += (size_t)N_NODES*4;
    float4*         cmat  = (float4*)base;         base += 448;
    float*          G     = (float*)base;          base += 4096;
    int*            bucketFill = (int*)base;       base += 2048;
    int*            flag  = (int*)base;            base += 16;

    k_init<<<1, 256, 0, stream>>>(qw, ei, cmat, flag, bucketFill, G);
    k_part<<<NCHUNK, 256, 0, stream>>>(ei, flag, bucketFill, pairs);
    k_sort<<<NB_BUCKETS, 256, 0, stream>>>(pairs, bucketFill, csr, nodeOff, dinv);
    k_feat<<<N_NODES/4, 256, 0, stream>>>(x, dinv, cmat, z);
    k_gather<<<(N_NODES*4 + 255)/256, 256, 0, stream>>>(csr, nodeOff, bucketFill, z, dinv, ob);
    k_gram<<<196, 256, 0, stream>>>(ob, G);
    k_mlp<<<1, 256, 0, stream>>>(G, W1, b1, W2, b2, outp);
}

// Round 9
// 209.712 us; speedup vs baseline: 2.2736x; 1.0802x over previous
//
#include <hip/hip_runtime.h>
#include <hip/hip_fp16.h>
#include <math.h>

#define N_NODES 50000
#define N_EDGES 1600000
#define BSHIFT 6            // bucket = dst>>6 (64 nodes per bucket)
#define NB_BUCKETS 782      // ceil(50000/64)
#define PART_CHUNK 8192
#define NCHUNK 196          // ceil(N_EDGES / PART_CHUNK)
#define CAP 3072            // per-bucket slot stride; mean 2048, sigma ~45
#define ZSTRIDE 32          // z row = 32 halves = 64B, one cache line

// ---------- DPP helpers (VALU-pipe cross-lane, no LDS) ----------
template<int CTRL>
__device__ inline float dpp_mov(float x){
    return __int_as_float(__builtin_amdgcn_update_dpp(0, __float_as_int(x), CTRL, 0xf, 0xf, false));
}
__device__ inline float wave_sum_dpp(float x){
    x += dpp_mov<0x111>(x);   // row_shr:1
    x += dpp_mov<0x112>(x);   // row_shr:2
    x += dpp_mov<0x114>(x);   // row_shr:4
    x += dpp_mov<0x118>(x);   // row_shr:8
    x += dpp_mov<0x142>(x);   // row_bcast:15
    x += dpp_mov<0x143>(x);   // row_bcast:31
    return x;
}
__device__ inline float lane63(float x){
    return __int_as_float(__builtin_amdgcn_readlane(__float_as_int(x), 63));
}
#define DPP_XOR1 0xB1   // quad_perm [1,0,3,2]
#define DPP_XOR2 0x4E   // quad_perm [2,3,0,1]

// ---------- complex 2x2 helpers ----------
struct C2 { float x, y; };
__device__ inline C2 mkc(float x, float y){ C2 r; r.x=x; r.y=y; return r; }
__device__ inline C2 cmul(C2 a, C2 b){ return mkc(a.x*b.x - a.y*b.y, a.x*b.y + a.y*b.x); }
__device__ inline C2 cadd(C2 a, C2 b){ return mkc(a.x+b.x, a.y+b.y); }

// ---------- K0: probe dtype + pair coefficients + zero bucketFill/G ----------
__global__ __launch_bounds__(256) void k_init(const float* __restrict__ qw,
        const void* __restrict__ ei, float4* __restrict__ cmat,
        int* __restrict__ flag, int* __restrict__ bucketFill, float* __restrict__ G){
    int t = threadIdx.x;
    for (int i = t; i < NB_BUCKETS; i += 256) bucketFill[i] = 0;
    for (int i = t; i < 784; i += 256) G[i] = 0.f;
    if (t == 255){
        const long long* e64 = (const long long*)ei;
        int ok = 1;
        for (int i = 0; i < 64; i++){
            long long v = e64[i];
            if (v < 0 || v >= N_NODES) ok = 0;
        }
        flag[0] = ok;
    }
    if (t < 28){
        int p = t;
        int a = 0; { int rem = p, q = 0; while (rem >= 7 - q){ rem -= 7 - q; q++; } a = q; }
        C2 M00 = mkc(1,0), M01 = mkc(0,0), M10 = mkc(0,0), M11 = mkc(1,0);
        for (int k = 0; k < 6; k++){
            float th = 0.5f * qw[p*6 + k];
            float s, c; sincosf(th, &s, &c);
            C2 R00, R01, R10, R11;
            int type = k % 3;
            if (type == 0){      // Rx
                R00 = mkc(c,0); R01 = mkc(0,-s); R10 = mkc(0,-s); R11 = mkc(c,0);
            } else if (type == 1){ // Ry
                R00 = mkc(c,0); R01 = mkc(-s,0); R10 = mkc(s,0); R11 = mkc(c,0);
            } else {             // Rz
                R00 = mkc(c,-s); R01 = mkc(0,0); R10 = mkc(0,0); R11 = mkc(c,s);
            }
            C2 N00 = cadd(cmul(R00,M00), cmul(R01,M10));
            C2 N01 = cadd(cmul(R00,M01), cmul(R01,M11));
            C2 N10 = cadd(cmul(R10,M00), cmul(R11,M10));
            C2 N11 = cadd(cmul(R10,M01), cmul(R11,M11));
            M00=N00; M01=N01; M10=N10; M11=N11;
        }
        float B00  = (M00.x*M00.x + M00.y*M00.y) - (M10.x*M10.x + M10.y*M10.y);
        float B11  = (M01.x*M01.x + M01.y*M01.y) - (M11.x*M11.x + M11.y*M11.y);
        float B01r = (M00.x*M01.x + M00.y*M01.y) - (M10.x*M11.x + M10.y*M11.y);
        cmat[p] = make_float4(0.5f + 0.5f*B11, 0.5f*(B00 - B11), B01r, (float)a);
    }
}

__device__ inline int get_edge(const void* ei, int is64, long long idx){
    if (is64) return (int)((const long long*)ei)[idx];
    return ((const int*)ei)[idx];
}

// ---------- one-pass partition: 1024 threads, edges in registers ----------
// pairs bucket-major with stride CAP; entry = (dst<<16)|src
__global__ __launch_bounds__(1024) void k_part(const void* __restrict__ ei,
        const int* __restrict__ flag, int* __restrict__ bucketFill,
        unsigned* __restrict__ pairs){
    __shared__ int hist[NB_BUCKETS];
    __shared__ int cntb[NB_BUCKETS];
    __shared__ int cursor[NB_BUCKETS];
    __shared__ int copyBase[NB_BUCKETS];
    __shared__ unsigned sorted[PART_CHUNK];
    int tid = threadIdx.x, c = blockIdx.x;
    long long base = (long long)c * PART_CHUNK;
    int cnt = (int)((N_EDGES - base < PART_CHUNK) ? (N_EDGES - base) : PART_CHUNK);
    int is64 = flag[0];
    // load this thread's 8 edges once (coalesced, stride 1024)
    unsigned ds[8], sr[8];
    #pragma unroll
    for (int k = 0; k < 8; k++){
        int i = tid + 1024*k;
        if (i < cnt){
            ds[k] = (unsigned)get_edge(ei, is64, (long long)N_EDGES + base + i);
            sr[k] = (unsigned)get_edge(ei, is64, base + i);
        } else ds[k] = 0xffffffffu;
    }
    if (tid < NB_BUCKETS) hist[tid] = 0;
    __syncthreads();
    #pragma unroll
    for (int k = 0; k < 8; k++)
        if (ds[k] != 0xffffffffu) atomicAdd(&hist[ds[k] >> BSHIFT], 1);
    __syncthreads();
    if (tid < NB_BUCKETS) cntb[tid] = hist[tid];
    __syncthreads();
    for (int ofs = 1; ofs < NB_BUCKETS; ofs <<= 1){   // inclusive scan, 1 elem/thread
        int v = 0; bool a = tid < NB_BUCKETS;
        if (a) v = hist[tid] + (tid >= ofs ? hist[tid - ofs] : 0);
        __syncthreads();
        if (a) hist[tid] = v;
        __syncthreads();
    }
    if (tid < NB_BUCKETS){
        int cb = cntb[tid];
        int ls = hist[tid] - cb;                       // local exclusive start
        int gbase = tid*CAP + atomicAdd(&bucketFill[tid], cb);
        copyBase[tid] = gbase - ls;
        cursor[tid] = ls;
    }
    __syncthreads();
    #pragma unroll
    for (int k = 0; k < 8; k++){
        if (ds[k] != 0xffffffffu){
            int pos = atomicAdd(&cursor[ds[k] >> BSHIFT], 1);
            sorted[pos] = (ds[k] << 16) | sr[k];
        }
    }
    __syncthreads();
    for (int i = tid; i < cnt; i += 1024){
        unsigned v = sorted[i];
        int b = (int)(v >> 22);                        // dst>>6
        pairs[copyBase[b] + i] = v;
    }
}

// ---------- per-bucket counting sort -> ushort CSR + nodeOff + dinv ----------
__global__ __launch_bounds__(256) void k_sort(const unsigned* __restrict__ pairs,
        const int* __restrict__ bucketFill, unsigned short* __restrict__ csr,
        int* __restrict__ nodeOff, float* __restrict__ dinv){
    __shared__ unsigned short sorted[CAP];
    __shared__ int hist[64];
    __shared__ int cursor[64];
    int b = blockIdx.x, t = threadIdx.x;
    int s0 = b*CAP;
    int cnt = bucketFill[b];
    if (cnt > CAP) cnt = CAP;
    if (t < 64) hist[t] = 0;
    __syncthreads();
    for (int i = t; i < cnt; i += 256){
        unsigned v = pairs[s0 + i];
        atomicAdd(&hist[(v >> 16) & 63], 1);
    }
    __syncthreads();
    int mycnt = (t < 64) ? hist[t] : 0;
    for (int ofs = 1; ofs < 64; ofs <<= 1){
        int nv = 0;
        if (t < 64) nv = hist[t] + (t >= ofs ? hist[t - ofs] : 0);
        __syncthreads();
        if (t < 64) hist[t] = nv;
        __syncthreads();
    }
    if (t < 64){
        cursor[t] = hist[t] - mycnt;               // exclusive start
        int n = b*64 + t;
        if (n < N_NODES){
            nodeOff[n] = s0 + hist[t] - mycnt;     // index into csr (bucket-major)
            dinv[n] = rsqrtf((float)(mycnt + 1));
        }
    }
    __syncthreads();
    for (int i = t; i < cnt; i += 256){
        unsigned v = pairs[s0 + i];
        int d = (v >> 16) & 63;
        int pos = atomicAdd(&cursor[d], 1);
        sorted[pos] = (unsigned short)(v & 0xffffu);
    }
    __syncthreads();
    for (int i = t; i < cnt; i += 256) csr[s0 + i] = sorted[i];
}

// ---------- quantum features: one wave per node, DPP reductions, fp16 z ----------
__global__ __launch_bounds__(256) void k_feat(const float* __restrict__ x,
        const float* __restrict__ dinv, const float4* __restrict__ cmat,
        __half* __restrict__ z){
    int wave = threadIdx.x >> 6;
    int lane = threadIdx.x & 63;
    int n = blockIdx.x*4 + wave;
    const float4 v = ((const float4*)(x + (size_t)n*256))[lane];
    float persq = v.x*v.x + v.y*v.y + v.z*v.z + v.w*v.w;

    float red[15];
    red[0] = persq;
    red[1] = v.x*v.x + v.y*v.y;        // S0 qubit6
    red[2] = v.x*v.z + v.y*v.w;        // X qubit6
    {   // j=0: xor mask 1 via DPP quad_perm
        float px = dpp_mov<DPP_XOR1>(v.x), py = dpp_mov<DPP_XOR1>(v.y);
        float pz = dpp_mov<DPP_XOR1>(v.z), pw = dpp_mov<DPP_XOR1>(v.w);
        red[3] = v.x*px + v.y*py + v.z*pz + v.w*pw;
        red[9] = (lane & 1) ? 0.f : persq;
    }
    {   // j=1: xor mask 2 via DPP quad_perm
        float px = dpp_mov<DPP_XOR2>(v.x), py = dpp_mov<DPP_XOR2>(v.y);
        float pz = dpp_mov<DPP_XOR2>(v.z), pw = dpp_mov<DPP_XOR2>(v.w);
        red[4] = v.x*px + v.y*py + v.z*pz + v.w*pw;
        red[10] = (lane & 2) ? 0.f : persq;
    }
    #pragma unroll
    for (int j = 2; j < 6; j++){
        float px = __shfl_xor(v.x, 1 << j), py = __shfl_xor(v.y, 1 << j);
        float pz = __shfl_xor(v.z, 1 << j), pw = __shfl_xor(v.w, 1 << j);
        red[3 + j] = v.x*px + v.y*py + v.z*pz + v.w*pw;
        red[9 + j] = ((lane >> j) & 1) ? 0.0f : persq;
    }
    float S[15];
    #pragma unroll
    for (int k = 0; k < 15; k++) S[k] = lane63(wave_sum_dpp(red[k]));

    if (lane < 28){
        float4 cm = cmat[lane];
        int ap = (int)cm.w;
        float S0a = (ap==6) ? S[1] :
                    (ap==0 ? S[14] : ap==1 ? S[13] : ap==2 ? S[12] :
                     ap==3 ? S[11] : ap==4 ? S[10] : S[9]);
        float Xa  = (ap==6) ? S[2] :
                    0.5f*(ap==0 ? S[8] : ap==1 ? S[7] : ap==2 ? S[6] :
                          ap==3 ? S[5] : ap==4 ? S[4] : S[3]);
        float feat = cm.x + (cm.y*S0a + cm.z*Xa) / S[0];
        z[(size_t)n*ZSTRIDE + lane] = __float2half(dinv[n] * feat);
    } else if (lane < 32){
        z[(size_t)n*ZSTRIDE + lane] = __float2half(0.f);   // zero pad
    }
}

// ---------- GCN aggregate + relu: 4 threads/node, fp16 rows, DPP combine ----------
__device__ inline void acc_pack(unsigned u, float& a, float& b){
    float2 f = __half22float2(__builtin_bit_cast(__half2, u));
    a += f.x; b += f.y;
}
__device__ inline void acc_row(const uint4* rp, float* acc /*32*/){
    uint4 w0 = rp[0], w1 = rp[1], w2 = rp[2], w3 = rp[3];
    acc_pack(w0.x, acc[0],  acc[1]);  acc_pack(w0.y, acc[2],  acc[3]);
    acc_pack(w0.z, acc[4],  acc[5]);  acc_pack(w0.w, acc[6],  acc[7]);
    acc_pack(w1.x, acc[8],  acc[9]);  acc_pack(w1.y, acc[10], acc[11]);
    acc_pack(w1.z, acc[12], acc[13]); acc_pack(w1.w, acc[14], acc[15]);
    acc_pack(w2.x, acc[16], acc[17]); acc_pack(w2.y, acc[18], acc[19]);
    acc_pack(w2.z, acc[20], acc[21]); acc_pack(w2.w, acc[22], acc[23]);
    acc_pack(w3.x, acc[24], acc[25]); acc_pack(w3.y, acc[26], acc[27]);
    acc_pack(w3.z, acc[28], acc[29]); acc_pack(w3.w, acc[30], acc[31]);
}

__global__ __launch_bounds__(256) void k_gather(const unsigned short* __restrict__ csr,
        const int* __restrict__ nodeOff, const int* __restrict__ bucketFill,
        const __half* __restrict__ z, const float* __restrict__ dinv,
        float* __restrict__ out){
    int g = blockIdx.x*256 + threadIdx.x;
    int n = g >> 2, sub = g & 3;
    if (n >= N_NODES) return;
    int b = n >> 6, d = n & 63;
    int beg = nodeOff[n];
    int end = (d == 63 || n == N_NODES - 1) ? b*CAP + min(bucketFill[b], CAP)
                                            : nodeOff[n + 1];
    float acc[32];
    #pragma unroll
    for (int k = 0; k < 32; k++) acc[k] = 0.f;
    for (int i = beg + sub; i < end; i += 4){
        int src = csr[i];
        acc_row((const uint4*)(z + (size_t)src*ZSTRIDE), acc);
    }
    if (sub == 3) acc_row((const uint4*)(z + (size_t)n*ZSTRIDE), acc);  // self loop
    #pragma unroll
    for (int k = 0; k < 32; k++){
        acc[k] += dpp_mov<DPP_XOR1>(acc[k]);
        acc[k] += dpp_mov<DPP_XOR2>(acc[k]);
    }
    if (sub == 0){
        float dv = dinv[n];
        float4* o = (float4*)(out + (size_t)n*28);
        #pragma unroll
        for (int q = 0; q < 7; q++)
            o[q] = make_float4(fmaxf(acc[4*q+0]*dv, 0.f), fmaxf(acc[4*q+1]*dv, 0.f),
                               fmaxf(acc[4*q+2]*dv, 0.f), fmaxf(acc[4*q+3]*dv, 0.f));
    }
}

// ---------- Gram: 2x2 register tiling ----------
__global__ __launch_bounds__(256) void k_gram(const float* __restrict__ out, float* __restrict__ G){
    __shared__ float buf[64*28];
    int tid = threadIdx.x;
    bool val = tid < 196;
    int ti = val ? tid / 14 : 0, tj = val ? tid % 14 : 0;
    int i0 = 2*ti, j0 = 2*tj;
    float c00 = 0.f, c01 = 0.f, c10 = 0.f, c11 = 0.f;
    int nchunks = (N_NODES + 63) / 64;
    for (int ch = blockIdx.x; ch < nchunks; ch += gridDim.x){
        int base = ch * 64;
        int total = (N_NODES - base < 64 ? N_NODES - base : 64) * 28;
        __syncthreads();
        for (int t = tid; t < 64*28; t += 256)
            buf[t] = (t < total) ? out[(size_t)base*28 + t] : 0.f;
        __syncthreads();
        for (int nn = 0; nn < 64; nn++){
            const float* r = buf + nn*28;
            float a0 = r[i0], a1 = r[i0+1], b0 = r[j0], b1 = r[j0+1];
            c00 += a0*b0; c01 += a0*b1; c10 += a1*b0; c11 += a1*b1;
        }
    }
    if (val){
        atomicAdd(&G[(i0  )*28 + j0  ], c00);
        atomicAdd(&G[(i0  )*28 + j0+1], c01);
        atomicAdd(&G[(i0+1)*28 + j0  ], c10);
        atomicAdd(&G[(i0+1)*28 + j0+1], c11);
    }
}

// ---------- fused MLP ----------
__global__ __launch_bounds__(256) void k_mlp(const float* __restrict__ G,
        const float* __restrict__ W1, const float* __restrict__ b1,
        const float* __restrict__ W2, const float* __restrict__ b2,
        float* __restrict__ outp){
    __shared__ float part[256];
    __shared__ float h[128];
    int t = threadIdx.x;
    int j = t & 127, halfsel = t >> 7;
    const float* w = W1 + (size_t)j*784 + halfsel*392;
    const float* g = G + halfsel*392;
    float s = 0.f;
    for (int i = 0; i < 392; i++) s += g[i] * w[i];
    part[t] = s;
    __syncthreads();
    if (t < 128) h[t] = fmaxf(part[t] + part[t+128] + b1[t], 0.f) * W2[t];
    __syncthreads();
    for (int ofs = 64; ofs > 0; ofs >>= 1){
        if (t < ofs) h[t] += h[t + ofs];
        __syncthreads();
    }
    if (t == 0) outp[0] = 1.f / (1.f + expf(-(h[0] + b2[0])));
}

extern "C" void kernel_launch(void* const* d_in, const int* in_sizes, int n_in,
                              void* d_out, int out_size, void* d_ws, size_t ws_size,
                              hipStream_t stream){
    const float* x  = (const float*)d_in[0];
    const void*  ei = d_in[1];
    const float* qw = (const float*)d_in[2];
    const float* W1 = (const float*)d_in[3];
    const float* b1 = (const float*)d_in[4];
    const float* W2 = (const float*)d_in[5];
    const float* b2 = (const float*)d_in[6];
    float* outp = (float*)d_out;

    char* base = (char*)d_ws;
    __half*         z     = (__half*)base;         base += (size_t)N_NODES*ZSTRIDE*2;     // 3.2 MB
    float*          ob    = (float*)base;          base += (size_t)N_NODES*28*4;          // 5.6 MB
    unsigned*       pairs = (unsigned*)base;       base += (size_t)NB_BUCKETS*CAP*4;      // 9.6 MB
    unsigned short* csr   = (unsigned short*)base; base += (size_t)NB_BUCKETS*CAP*2;      // 4.8 MB
    int*            nodeOff = (int*)base;          base += (size_t)N_NODES*4;
    float*          dinv  = (float*)base;          base += (size_t)N_NODES*4;
    float4*         cmat  = (float4*)base;         base += 448;
    float*          G     = (float*)base;          base += 4096;
    int*            bucketFill = (int*)base;       base += 4096;
    int*            flag  = (int*)base;            base += 16;

    k_init<<<1, 256, 0, stream>>>(qw, ei, cmat, flag, bucketFill, G);
    k_part<<<NCHUNK, 1024, 0, stream>>>(ei, flag, bucketFill, pairs);
    k_sort<<<NB_BUCKETS, 256, 0, stream>>>(pairs, bucketFill, csr, nodeOff, dinv);
    k_feat<<<N_NODES/4, 256, 0, stream>>>(x, dinv, cmat, z);
    k_gather<<<(N_NODES*4 + 255)/256, 256, 0, stream>>>(csr, nodeOff, bucketFill, z, dinv, ob);
    k_gram<<<196, 256, 0, stream>>>(ob, G);
    k_mlp<<<1, 256, 0, stream>>>(G, W1, b1, W2, b2, outp);
}